// Round 11
// baseline (566.537 us; speedup 1.0000x reference)
//
#include <hip/hip_runtime.h>

// LSTMNet: SEQ=600, B=4096, IN=6, H=30, OUT=61, fp32 in/out.
// MFMA design M2.1: one wave = 16 batch elements; 256 single-wave blocks.
// Per gate q and M-tile m:  C[q][m] = A_h[q][m] x B_h([h;pad;1]^T) + xacc[q][m]
// where xacc[q][m] = A_x[q][m] x B_x(x^T) is PRECOMPUTED during the previous
// step (x is prefetched one step ahead; the x-MFMAs are independent of the
// h-recurrence) and enters as the MFMA C-operand -> per-step critical chain
// is cvtpk -> bpermute -> ONE mfma -> nonlinearity.
// Nonlinearity computed as 16 independent f32x2 sigm/tanh chains first
// (trans-pipe streaming), then the short c/h dependency tail.
// C layout (m89): col=lane&15=batch, row=(lane>>4)*4+reg=out-unit -> all 4
// gates of a (unit,batch) sit in the same lane/reg: c/h update lane-local.
// Weights are MFMA A-operands -> AGPR residency is free (R1-9 lesson).

#define SEQ   600
#define BATCH 4096
#define INP   6
#define HID   30
#define NOUT  61
#define LOG2E  1.4426950408889634f
#define LOG2E2 2.8853900817779268f

typedef __fp16 f16;
typedef f16  f16x2 __attribute__((ext_vector_type(2)));
typedef f16  f16x8 __attribute__((ext_vector_type(8)));
typedef float f32x2 __attribute__((ext_vector_type(2)));
typedef float f32x4 __attribute__((ext_vector_type(4)));

__device__ __forceinline__ float rcp_(float x)  { return __builtin_amdgcn_rcpf(x); }
__device__ __forceinline__ float exp2_(float x) { return __builtin_amdgcn_exp2f(x); }
__device__ __forceinline__ unsigned cvtpk(float a, float b) {
    union { f16x2 h; unsigned u; } c;
    c.h = __builtin_amdgcn_cvt_pkrtz(a, b);
    return c.u;
}
__device__ __forceinline__ f16x8 mk8(unsigned a, unsigned b, unsigned c, unsigned d) {
    union { unsigned u[4]; f16x8 v; } x;
    x.u[0] = a; x.u[1] = b; x.u[2] = c; x.u[3] = d;
    return x.v;
}
__device__ __forceinline__ f32x2 sigm2(f32x2 x) {
    f32x2 t = x * (-LOG2E);
    f32x2 e; e.x = exp2_(t.x); e.y = exp2_(t.y);
    e = e + 1.0f;
    f32x2 r; r.x = rcp_(e.x); r.y = rcp_(e.y);
    return r;
}
__device__ __forceinline__ f32x2 tanh2(f32x2 x) {
    f32x2 t = x * LOG2E2;
    f32x2 e; e.x = exp2_(t.x); e.y = exp2_(t.y);
    e = e + 1.0f;
    f32x2 r;
    r.x = fmaf(-2.0f, rcp_(e.x), 1.0f);
    r.y = fmaf(-2.0f, rcp_(e.y), 1.0f);
    return r;
}

extern "C" __global__ void __launch_bounds__(64, 1)
lstm_mfma2(const float* __restrict__ X,   const float* __restrict__ Wih,
           const float* __restrict__ Whh, const float* __restrict__ bih,
           const float* __restrict__ bhh, const float* __restrict__ W1,
           const float* __restrict__ b1,  const float* __restrict__ W2,
           const float* __restrict__ b2,  float* __restrict__ out)
{
    __shared__ float h2s[16][36];   // final h, f32 (padded rows)
    __shared__ float o1s[16][36];   // fc1 activations

    const int l  = threadIdx.x;       // 0..63
    const int b  = l & 15;            // batch slot (C-col role)
    const int g  = l >> 4;            // k-group (A/B row-group role)
    const int bg = blockIdx.x * 16 + b;   // this lane's batch element

    // ---- pack A fragments (one-time). A row = l&15 (out-unit), k = 8g+j ----
    f16x8 Ah[4][2], Ax[4][2];
    #pragma unroll
    for (int q = 0; q < 4; ++q) {
        #pragma unroll
        for (int m = 0; m < 2; ++m) {
            const int ou  = 16 * m + b;        // out-unit this lane supplies
            const bool ov = (ou < HID);
            unsigned dh[4], dx[4];
            #pragma unroll
            for (int jp = 0; jp < 4; ++jp) {
                const int k0 = 8 * g + 2 * jp, k1 = k0 + 1;
                float v0 = (ov && k0 < HID) ? Whh[(q * HID + ou) * HID + k0] : 0.f;
                float v1 = (ov && k1 < HID) ? Whh[(q * HID + ou) * HID + k1]
                         : ((ov && k1 == 31) ? (bih[q * HID + ou] + bhh[q * HID + ou]) : 0.f);
                dh[jp] = cvtpk(v0, v1);
                float w0 = (ov && k0 < INP) ? Wih[(q * HID + ou) * INP + k0] : 0.f;
                float w1 = (ov && k1 < INP) ? Wih[(q * HID + ou) * INP + k1] : 0.f;
                dx[jp] = cvtpk(w0, w1);
            }
            Ah[q][m] = mk8(dh[0], dh[1], dh[2], dh[3]);
            Ax[q][m] = mk8(dx[0], dx[1], dx[2], dx[3]);
        }
    }

    // ---- bpermute wiring (verified R10): B dword d = h-pair (4g+d) ----
    const int a0 = ((((2 * g) + 0) & 3) * 16 + b) * 4;
    const int a1 = ((((2 * g) + 1) & 3) * 16 + b) * 4;
    const bool lo   = (g < 2);
    const bool isg0 = (g == 0);
    const bool isg3 = (g == 3);

    unsigned P0 = 0, P1 = 0, P2 = 0, P3 = 0;   // h = 0 at t = 0
    f32x2 cst[4] = {{0.f,0.f},{0.f,0.f},{0.f,0.f},{0.f,0.f}};
    f32x2 hv[4]  = {{0.f,0.f},{0.f,0.f},{0.f,0.f},{0.f,0.f}};

    // x(t=0) and xacc for step 0
    f32x2 xa = *(const f32x2*)(X + (size_t)bg * INP);
    f32x2 xb = *(const f32x2*)(X + (size_t)bg * INP + 2);
    f32x2 xc = *(const f32x2*)(X + (size_t)bg * INP + 4);
    const float* pn = X + ((size_t)BATCH + bg) * INP;   // t = 1

    f32x4 xcur[4][2], xnxt[4][2];

    #define XACC(DST, XA, XB, XC) do {                                         \
        const unsigned cv0 = cvtpk((XA).x, (XA).y);                            \
        const unsigned cv1 = cvtpk((XB).x, (XB).y);                            \
        const unsigned cv2 = cvtpk((XC).x, (XC).y);                            \
        const f16x8 Bx = mk8(isg0 ? cv0 : 0u, isg0 ? cv1 : 0u,                 \
                             isg0 ? cv2 : 0u, 0u);                             \
        _Pragma("unroll")                                                      \
        for (int q = 0; q < 4; ++q) {                                          \
            _Pragma("unroll")                                                  \
            for (int m = 0; m < 2; ++m) {                                      \
                f32x4 z = {0.f, 0.f, 0.f, 0.f};                                \
                DST[q][m] = __builtin_amdgcn_mfma_f32_16x16x32_f16(            \
                                Ax[q][m], Bx, z, 0, 0, 0);                     \
            }                                                                  \
        }                                                                      \
    } while (0)

    XACC(xcur, xa, xb, xc);   // xacc for t = 0

    #define STEP_H() do {                                                      \
        /* gather h into B-fragment */                                         \
        const unsigned s00 = (unsigned)__builtin_amdgcn_ds_bpermute(a0,(int)P0);\
        const unsigned s01 = (unsigned)__builtin_amdgcn_ds_bpermute(a0,(int)P1);\
        const unsigned s02 = (unsigned)__builtin_amdgcn_ds_bpermute(a0,(int)P2);\
        const unsigned s03 = (unsigned)__builtin_amdgcn_ds_bpermute(a0,(int)P3);\
        const unsigned s10 = (unsigned)__builtin_amdgcn_ds_bpermute(a1,(int)P0);\
        const unsigned s11 = (unsigned)__builtin_amdgcn_ds_bpermute(a1,(int)P1);\
        const unsigned s12 = (unsigned)__builtin_amdgcn_ds_bpermute(a1,(int)P2);\
        const unsigned s13 = (unsigned)__builtin_amdgcn_ds_bpermute(a1,(int)P3);\
        const unsigned d0 = lo ? s00 : s02;                                    \
        const unsigned d1 = lo ? s01 : s03;                                    \
        const unsigned d2 = lo ? s10 : s12;                                    \
        unsigned d3 = lo ? s11 : s13;                                          \
        d3 = isg3 ? 0x3C000000u : d3;   /* k-slots (30,31) = (0, 1.0) */       \
        const f16x8 Bh = mk8(d0, d1, d2, d3);                                  \
        f32x4 Cq[4][2];                                                        \
        _Pragma("unroll")                                                      \
        for (int q = 0; q < 4; ++q) {                                          \
            _Pragma("unroll")                                                  \
            for (int m = 0; m < 2; ++m)                                        \
                Cq[q][m] = __builtin_amdgcn_mfma_f32_16x16x32_f16(             \
                               Ah[q][m], Bh, xcur[q][m], 0, 0, 0);             \
        }                                                                      \
        /* 16 independent nonlin chains first (trans streaming) */             \
        f32x2 SI[4], SF[4], SO[4], TG[4];                                      \
        _Pragma("unroll")                                                      \
        for (int m = 0; m < 2; ++m) {                                          \
            _Pragma("unroll")                                                  \
            for (int rp = 0; rp < 2; ++rp) {                                   \
                const int p = m * 2 + rp;                                      \
                SI[p] = sigm2(f32x2{Cq[0][m][2*rp], Cq[0][m][2*rp+1]});        \
                SF[p] = sigm2(f32x2{Cq[1][m][2*rp], Cq[1][m][2*rp+1]});        \
                TG[p] = tanh2(f32x2{Cq[2][m][2*rp], Cq[2][m][2*rp+1]});        \
                SO[p] = sigm2(f32x2{Cq[3][m][2*rp], Cq[3][m][2*rp+1]});        \
            }                                                                  \
        }                                                                      \
        _Pragma("unroll")                                                      \
        for (int p = 0; p < 4; ++p) {                                          \
            cst[p] = SF[p] * cst[p] + SI[p] * TG[p];                           \
            hv[p]  = SO[p] * tanh2(cst[p]);                                    \
        }                                                                      \
        P0 = cvtpk(hv[0].x, hv[0].y);                                          \
        P1 = cvtpk(hv[1].x, hv[1].y);                                          \
        P2 = cvtpk(hv[2].x, hv[2].y);                                          \
        P3 = cvtpk(hv[3].x, hv[3].y);                                          \
    } while (0)

    for (int t = 0; t < SEQ - 1; ++t) {
        // prefetch x(t+1) and precompute its projection (independent of h-chain)
        const f32x2 ya = *(const f32x2*)pn;
        const f32x2 yb = *(const f32x2*)(pn + 2);
        const f32x2 yc = *(const f32x2*)(pn + 4);
        pn += (size_t)BATCH * INP;
        XACC(xnxt, ya, yb, yc);

        STEP_H();   // step t (consumes xcur)

        #pragma unroll
        for (int q = 0; q < 4; ++q)
            #pragma unroll
            for (int m = 0; m < 2; ++m) xcur[q][m] = xnxt[q][m];
    }
    STEP_H();   // t = SEQ-1
    #undef STEP_H
    #undef XACC

    // ---- stash final h (f32) to LDS: lane holds units {4g..4g+3, 16+4g..} ----
    *(f32x2*)&h2s[b][4 * g]      = hv[0];
    *(f32x2*)&h2s[b][4 * g + 2]  = hv[1];
    *(f32x2*)&h2s[b][16 + 4 * g] = hv[2];
    *(f32x2*)&h2s[b][18 + 4 * g] = hv[3];
    __builtin_amdgcn_s_waitcnt(0);           // single wave: drain lgkm
    __builtin_amdgcn_sched_barrier(0);

    // ---- FC1: o1[b][u] for u = g + 4r ----
    f32x4 hr[8];
    #pragma unroll
    for (int i = 0; i < 8; ++i) hr[i] = *(const f32x4*)&h2s[b][4 * i];
    #pragma unroll
    for (int r = 0; r < 8; ++r) {
        const int u  = g + 4 * r;
        const int uc = (u < HID) ? u : (HID - 1);
        float acc = b1[uc];
        const float* wr = W1 + uc * HID;
        #pragma unroll
        for (int k = 0; k < HID; ++k) acc = fmaf(wr[k], hr[k >> 2][k & 3], acc);
        if (u < HID) o1s[b][u] = acc;
    }
    __builtin_amdgcn_s_waitcnt(0);
    __builtin_amdgcn_sched_barrier(0);

    // ---- FC2: out[bg][o] for o = g + 4r ----
    f32x4 orr[8];
    #pragma unroll
    for (int i = 0; i < 8; ++i) orr[i] = *(const f32x4*)&o1s[b][4 * i];
    #pragma unroll
    for (int r = 0; r < 16; ++r) {
        const int o  = g + 4 * r;
        const int oc = (o < NOUT) ? o : (NOUT - 1);
        float acc = b2[oc];
        const float* wr = W2 + oc * HID;
        #pragma unroll
        for (int k = 0; k < HID; ++k) acc = fmaf(wr[k], orr[k >> 2][k & 3], acc);
        if (o < NOUT) out[(size_t)bg * NOUT + o] = acc;
    }
}

extern "C" void kernel_launch(void* const* d_in, const int* in_sizes, int n_in,
                              void* d_out, int out_size, void* d_ws, size_t ws_size,
                              hipStream_t stream) {
    const float* X   = (const float*)d_in[0];
    const float* Wih = (const float*)d_in[1];
    const float* Whh = (const float*)d_in[2];
    const float* bih = (const float*)d_in[3];
    const float* bhh = (const float*)d_in[4];
    const float* W1  = (const float*)d_in[5];
    const float* b1  = (const float*)d_in[6];
    const float* W2  = (const float*)d_in[7];
    const float* b2  = (const float*)d_in[8];
    float* out = (float*)d_out;

    dim3 grid(BATCH / 16);   // 256 single-wave blocks (1 per CU)
    dim3 block(64);
    hipLaunchKernelGGL(lstm_mfma2, grid, block, 0, stream,
                       X, Wih, Whh, bih, bhh, W1, b1, W2, b2, out);
}

// Round 12
// 410.046 us; speedup vs baseline: 1.3816x; 1.3816x over previous
//
#include <hip/hip_runtime.h>

// LSTMNet: SEQ=600, B=4096, IN=6, H=30, OUT=61, fp32 in/out.
// COOPERATIVE MFMA design C1: 256 blocks x 4 waves; block owns 16 batch elems.
//   Wave q computes gate q (i,f,g,o) via v_mfma_f32_16x16x32_f16:
//     C[q][m] = Ah[q][m] x Bh([h;0;1]^T) + xacc[q][m],  m = unit-tile 0/1
//   Gates exchanged via LDS; nonlinearity split 2 elems/lane across ALL 4
//   waves (4 SIMDs) -> trans-pipe issue 640 -> 160 cy/step/wave (the R10
//   bottleneck). h written back as f16x2 pairs; next Bh = one ds_read_b128.
// Barriers: raw lgkmcnt(0)+s_barrier (NO vmcnt drain -> VMEM prefetch lives
// across barriers). X staged by global_load_lds ring (depth 8) guarded by
// counted vmcnt(7) (loads return in order); all 4 waves issue identical
// loads so each wave's own vmcnt guards its reads (dup writes benign).
// Fragment wiring identical to R10/R11 (verified absmax 1.95e-3):
//   A: row=lane&15 (unit), k=8g+j;  B: col=lane&15 (batch), k=8g+j,
//   dword d = k-pair (8g+2d, 8g+2d+1);  C: col=lane&15, row=4*(l>>4)+reg.
//   Bias folded at k=31 (Bh slot 31 = 1.0).

#define SEQ    600
#define BATCH  4096
#define INP    6
#define HID    30
#define NOUT   61
#define RD     8
#define LOG2E  1.4426950408889634f
#define LOG2E2 2.8853900817779268f

typedef __fp16 f16;
typedef f16  f16x2 __attribute__((ext_vector_type(2)));
typedef f16  f16x8 __attribute__((ext_vector_type(8)));
typedef float f32x2 __attribute__((ext_vector_type(2)));
typedef float f32x4 __attribute__((ext_vector_type(4)));

__device__ __forceinline__ float rcp_(float x)  { return __builtin_amdgcn_rcpf(x); }
__device__ __forceinline__ float exp2_(float x) { return __builtin_amdgcn_exp2f(x); }
__device__ __forceinline__ unsigned cvtpk(float a, float b) {
    union { f16x2 h; unsigned u; } c;
    c.h = __builtin_amdgcn_cvt_pkrtz(a, b);
    return c.u;
}
__device__ __forceinline__ f16x8 mk8(unsigned a, unsigned b, unsigned c, unsigned d) {
    union { unsigned u[4]; f16x8 v; } x;
    x.u[0] = a; x.u[1] = b; x.u[2] = c; x.u[3] = d;
    return x.v;
}
__device__ __forceinline__ f32x2 sigm2(f32x2 x) {
    f32x2 t = x * (-LOG2E);
    f32x2 e; e.x = exp2_(t.x); e.y = exp2_(t.y);
    e = e + 1.0f;
    f32x2 r; r.x = rcp_(e.x); r.y = rcp_(e.y);
    return r;
}
__device__ __forceinline__ f32x2 tanh2(f32x2 x) {
    f32x2 t = x * LOG2E2;
    f32x2 e; e.x = exp2_(t.x); e.y = exp2_(t.y);
    e = e + 1.0f;
    f32x2 r;
    r.x = fmaf(-2.0f, rcp_(e.x), 1.0f);
    r.y = fmaf(-2.0f, rcp_(e.y), 1.0f);
    return r;
}

// lgkm-only barrier: VMEM (ring prefetch) stays in flight across it.
#define BARRIER() do {                                          \
    asm volatile("s_waitcnt lgkmcnt(0)" ::: "memory");          \
    __builtin_amdgcn_s_barrier();                               \
    asm volatile("" ::: "memory");                              \
} while (0)

extern "C" __global__ void __launch_bounds__(256, 1)
lstm_coop(const float* __restrict__ X,   const float* __restrict__ Wih,
          const float* __restrict__ Whh, const float* __restrict__ bih,
          const float* __restrict__ bhh, const float* __restrict__ W1,
          const float* __restrict__ b1,  const float* __restrict__ W2,
          const float* __restrict__ b2,  float* __restrict__ out)
{
    __shared__ float    ringf[RD][96];       // x ring: 16 batch x 6 f32 per slot
    __shared__ float    gates[4][16][36];    // [gate][batch][unit(+pad)]
    __shared__ unsigned hbuf[16][20];        // [batch][unit-pair] f16x2 dwords
    __shared__ float    h32[16][36];         // final h (f32) for FC
    __shared__ float    o1s[16][36];         // fc1 activations

    const int tid  = threadIdx.x;
    const int w    = tid >> 6;        // wave index = gate q
    const int lane = tid & 63;
    const int g    = lane >> 4;       // k-group / row-group
    const int b    = lane & 15;       // batch col (MFMA roles); unit-pair (nonlin)
    const int bb   = 4 * w + g;       // nonlin batch
    const int blk  = blockIdx.x;
    const int q    = w;

    // ---- pack A fragments for gate q (R10-verified layout) ----
    f16x8 Ah[2], Ax[2];
    #pragma unroll
    for (int m = 0; m < 2; ++m) {
        const int ou = 16 * m + b;
        const bool ov = (ou < HID);
        unsigned dh[4], dx[4];
        #pragma unroll
        for (int jp = 0; jp < 4; ++jp) {
            const int k0 = 8 * g + 2 * jp, k1 = k0 + 1;
            float v0 = (ov && k0 < HID) ? Whh[(q * HID + ou) * HID + k0] : 0.f;
            float v1 = (ov && k1 < HID) ? Whh[(q * HID + ou) * HID + k1]
                     : ((ov && k1 == 31) ? (bih[q * HID + ou] + bhh[q * HID + ou]) : 0.f);
            dh[jp] = cvtpk(v0, v1);
            float u0 = (ov && k0 < INP) ? Wih[(q * HID + ou) * INP + k0] : 0.f;
            float u1 = (ov && k1 < INP) ? Wih[(q * HID + ou) * INP + k1] : 0.f;
            dx[jp] = cvtpk(u0, u1);
        }
        Ah[m] = mk8(dh[0], dh[1], dh[2], dh[3]);
        Ax[m] = mk8(dx[0], dx[1], dx[2], dx[3]);
    }

    // drain prologue VMEM so in-loop vmcnt counts ONLY ring loads
    asm volatile("s_waitcnt vmcnt(0)" ::: "memory");
    __builtin_amdgcn_sched_barrier(0);

    // h(0) = 0; pair 15 = (k30=0, k31=1.0) for the bias slot
    hbuf[bb][b] = (b == 15) ? 0x3C000000u : 0u;

    // issue ring loads for x(0..7): 24 lanes x 16B = 384B contiguous per slot
    #define RING_LOAD(SLOT, TT) do {                                           \
        const float* gsrc = X + ((size_t)(TT) * BATCH + (size_t)blk * 16) * INP\
                            + lane * 4;                                        \
        if (lane < 24)                                                         \
            __builtin_amdgcn_global_load_lds(                                  \
                (const __attribute__((address_space(1))) unsigned*)gsrc,       \
                (__attribute__((address_space(3))) unsigned*)&ringf[SLOT][0],  \
                16, 0, 0);                                                     \
    } while (0)

    #pragma unroll
    for (int s = 0; s < RD; ++s) RING_LOAD(s, s);

    f32x2 c  = {0.f, 0.f};
    f32x2 hl = {0.f, 0.f};
    f32x4 xaccA[2], xaccB[2];

    BARRIER();   // hbuf init visible to all waves

    #define XACC(DST, SLOT) do {                                               \
        const f32x2 xr0 = *(const f32x2*)&ringf[SLOT][b * 6 + 0];              \
        const f32x2 xr1 = *(const f32x2*)&ringf[SLOT][b * 6 + 2];              \
        const f32x2 xr2 = *(const f32x2*)&ringf[SLOT][b * 6 + 4];              \
        const unsigned e0 = cvtpk(xr0.x, xr0.y);                               \
        const unsigned e1 = cvtpk(xr1.x, xr1.y);                               \
        const unsigned e2 = cvtpk(xr2.x, xr2.y);                               \
        const f16x8 Bx = mk8(g == 0 ? e0 : 0u, g == 0 ? e1 : 0u,               \
                             g == 0 ? e2 : 0u, 0u);                            \
        const f32x4 zz = {0.f, 0.f, 0.f, 0.f};                                 \
        DST[0] = __builtin_amdgcn_mfma_f32_16x16x32_f16(Ax[0], Bx, zz, 0,0,0); \
        DST[1] = __builtin_amdgcn_mfma_f32_16x16x32_f16(Ax[1], Bx, zz, 0,0,0); \
    } while (0)

    // xacc for step 0 (slot 0 is the oldest of 8 in flight)
    asm volatile("s_waitcnt vmcnt(7)" ::: "memory");
    XACC(xaccA, 0);

    #define ITER(XC, XN, T) do {                                               \
        { int tl = (T) + RD; if (tl > SEQ - 1) tl = SEQ - 1;                   \
          RING_LOAD(((T) + RD) & 7, tl); }                                     \
        asm volatile("s_waitcnt vmcnt(7)" ::: "memory");                       \
        const uint4 hq = *(const uint4*)&hbuf[b][4 * g];                       \
        const f16x8 Bh = mk8(hq.x, hq.y, hq.z, hq.w);                          \
        const f32x4 C0 = __builtin_amdgcn_mfma_f32_16x16x32_f16(Ah[0], Bh, XC[0], 0,0,0); \
        const f32x4 C1 = __builtin_amdgcn_mfma_f32_16x16x32_f16(Ah[1], Bh, XC[1], 0,0,0); \
        XACC(XN, ((T) + 1) & 7);   /* x-projection for step T+1, off-chain */  \
        *(f32x4*)&gates[q][b][4 * g]      = C0;                                \
        *(f32x4*)&gates[q][b][16 + 4 * g] = C1;                                \
        BARRIER();                                                             \
        const f32x2 gi = *(const f32x2*)&gates[0][bb][2 * b];                  \
        const f32x2 gf = *(const f32x2*)&gates[1][bb][2 * b];                  \
        const f32x2 gg = *(const f32x2*)&gates[2][bb][2 * b];                  \
        const f32x2 go = *(const f32x2*)&gates[3][bb][2 * b];                  \
        const f32x2 si = sigm2(gi);                                            \
        const f32x2 sf = sigm2(gf);                                            \
        const f32x2 so = sigm2(go);                                            \
        const f32x2 tg = tanh2(gg);                                            \
        c  = sf * c + si * tg;                                                 \
        hl = so * tanh2(c);                                                    \
        hbuf[bb][b] = (b == 15) ? 0x3C000000u : cvtpk(hl.x, hl.y);             \
        BARRIER();                                                             \
    } while (0)

    for (int t2 = 0; t2 < SEQ; t2 += 2) {   // unroll-2: xacc ping-pong, no copies
        ITER(xaccA, xaccB, t2);
        ITER(xaccB, xaccA, t2 + 1);
    }
    #undef ITER
    #undef XACC
    #undef RING_LOAD

    // ---- epilogue: FC1 + FC2 (one-time) ----
    if (b < 15) *(f32x2*)&h32[bb][2 * b] = hl;   // units 2b,2b+1 of batch bb
    __syncthreads();

    {   // FC1: lane handles batch bb, output rows b and b+16
        float hr[HID];
        #pragma unroll
        for (int k = 0; k < HID; ++k) hr[k] = h32[bb][k];
        float a0 = b1[b];
        const float* w1r0 = W1 + b * HID;
        #pragma unroll
        for (int k = 0; k < HID; ++k) a0 = fmaf(w1r0[k], hr[k], a0);
        o1s[bb][b] = a0;
        if (b < 14) {
            float a1 = b1[b + 16];
            const float* w1r1 = W1 + (b + 16) * HID;
            #pragma unroll
            for (int k = 0; k < HID; ++k) a1 = fmaf(w1r1[k], hr[k], a1);
            o1s[bb][b + 16] = a1;
        }
    }
    __syncthreads();

    {   // FC2: rows b, b+16, b+32, b+48 (valid < 61)
        float orr[HID];
        #pragma unroll
        for (int k = 0; k < HID; ++k) orr[k] = o1s[bb][k];
        #pragma unroll
        for (int r = 0; r < 4; ++r) {
            const int o = b + 16 * r;
            if (o < NOUT) {
                float a2 = b2[o];
                const float* w2r = W2 + o * HID;
                #pragma unroll
                for (int k = 0; k < HID; ++k) a2 = fmaf(w2r[k], orr[k], a2);
                out[(size_t)(blk * 16 + bb) * NOUT + o] = a2;
            }
        }
    }
}

extern "C" void kernel_launch(void* const* d_in, const int* in_sizes, int n_in,
                              void* d_out, int out_size, void* d_ws, size_t ws_size,
                              hipStream_t stream) {
    const float* X   = (const float*)d_in[0];
    const float* Wih = (const float*)d_in[1];
    const float* Whh = (const float*)d_in[2];
    const float* bih = (const float*)d_in[3];
    const float* bhh = (const float*)d_in[4];
    const float* W1  = (const float*)d_in[5];
    const float* b1  = (const float*)d_in[6];
    const float* W2  = (const float*)d_in[7];
    const float* b2  = (const float*)d_in[8];
    float* out = (float*)d_out;

    dim3 grid(BATCH / 16);   // 256 blocks, 1 per CU
    dim3 block(256);         // 4 waves: one per SIMD, one per gate
    hipLaunchKernelGGL(lstm_coop, grid, block, 0, stream,
                       X, Wih, Whh, bih, bhh, W1, b1, W2, b2, out);
}

// Round 13
// 323.869 us; speedup vs baseline: 1.7493x; 1.2661x over previous
//
#include <hip/hip_runtime.h>

// LSTMNet: SEQ=600, B=4096, IN=6, H=30, OUT=61, fp32 in/out.
// FULL-ASM A4-f16: the entire 600-step recurrence is ONE inline-asm block.
// All loop-invariant state (72 weight dwords, biases, constants) are asm
// operands -> guaranteed arch-VGPR residency; the compiler cannot remat or
// AGPR-shuttle them (rounds 1-9 failure mode).
// Layout (R9-verified numerics): one wave = 2 batch elements (halves);
// lane = 32*half + u owns all 4 gate rows (i,f,g,o) of unit u.
//   gates: a_q = b_q + sum_j w_q[j] . h2[j] + sum_jj xw_q[jj] . x2[jj]
//   (v_dot2_f32_f16, f32 accumulate; exp2-based sigm/tanh)
// h exchange: ds_write_b16 h[u] -> 15x broadcast ds_read_b32 per step.
// x prefetch: 6x global_load_dword (saddr form), 1 step ahead; stride
// frozen via s_cselect near the end (no OOB reads).

#define SEQ   600
#define BATCH 4096
#define INP   6
#define HID   30
#define NOUT  61

typedef __fp16 f16;
typedef f16 f16x2 __attribute__((ext_vector_type(2)));
typedef unsigned u32;
typedef __attribute__((address_space(3))) f16 lds_f16;

__device__ __forceinline__ u32 cvtpk(float a, float b) {
    union { f16x2 h; u32 u; } c;
    c.h = __builtin_amdgcn_cvt_pkrtz(a, b);
    return c.u;
}

extern "C" __global__ void __launch_bounds__(64, 2)
lstm_asm(const float* __restrict__ X,   const float* __restrict__ Wih,
         const float* __restrict__ Whh, const float* __restrict__ bih,
         const float* __restrict__ bhh, const float* __restrict__ W1,
         const float* __restrict__ b1,  const float* __restrict__ W2,
         const float* __restrict__ b2,  float* __restrict__ out)
{
    __shared__ __align__(8) f16 h_sh[2][32];   // h rows (offsets 0, 64)
    __shared__ __align__(8) f16 trash[64];     // dump for inactive-lane writes
    __shared__ float o1_sh[2][32];

    const int lane = threadIdx.x;          // 0..63
    const int half = lane >> 5;
    const int u    = lane & 31;
    const int uu   = (u < HID) ? u : (HID - 1);
    const int b    = blockIdx.x * 2 + half;
    const bool act = (u < HID);

    h_sh[half][u] = (f16)0.f;

    // ---- pack weights (one-time, C++): gate-major, 15 h-pairs + 3 x-pairs ----
    u32 W[60], XW[12];
    #pragma unroll
    for (int g = 0; g < 4; ++g) {
        const float* r = Whh + (g * HID + uu) * HID;
        #pragma unroll
        for (int j = 0; j < 15; ++j) W[g * 15 + j] = cvtpk(r[2 * j], r[2 * j + 1]);
        const float* s = Wih + (g * HID + uu) * INP;
        #pragma unroll
        for (int j = 0; j < 3; ++j) XW[g * 3 + j] = cvtpk(s[2 * j], s[2 * j + 1]);
    }
    const float B0 = bih[0 * HID + uu] + bhh[0 * HID + uu];
    const float B1 = bih[1 * HID + uu] + bhh[1 * HID + uu];
    const float B2 = bih[2 * HID + uu] + bhh[2 * HID + uu];
    const float B3 = bih[3 * HID + uu] + bhh[3 * HID + uu];
    const float NL = -1.4426950408889634f;   // -log2(e)
    const float L2 = 2.8853900817779268f;    // 2*log2(e)

    // LDS byte offsets (address_space(3) cast -> raw DS offset; R12 precedent)
    const unsigned ha = (unsigned)(unsigned long long)(lds_f16*)&h_sh[half][0];
    const unsigned wa = act
        ? (unsigned)(unsigned long long)(lds_f16*)&h_sh[half][u]
        : (unsigned)(unsigned long long)(lds_f16*)&trash[lane];

    // x(0) loaded in C++; asm prefetches x(t+1) each iter via saddr+voff
    float x0 = X[(size_t)b * INP + 0], x1 = X[(size_t)b * INP + 1];
    float x2 = X[(size_t)b * INP + 2], x3 = X[(size_t)b * INP + 3];
    float x4 = X[(size_t)b * INP + 4], x5 = X[(size_t)b * INP + 5];
    const float* xbase = X + (size_t)blockIdx.x * 2 * INP;   // wave-uniform
    unsigned vo = (unsigned)(BATCH * INP * 4) + (unsigned)(half * INP * 4); // t=1

    // asm state (all "+v" so each gets its own arch VGPR)
    float a0=0,a1=0,a2=0,a3=0,a4=0,a5=0,a6=0,a7=0;
    float t0=0,t1=0,t2=0,t3=0,t4=0,t5=0,t6=0,t7=0;
    u32 h0=0,h1=0,h2=0,h3=0,h4=0,h5=0,h6=0,h7=0,h8=0,h9=0,h10=0,h11=0,h12=0,h13=0,h14=0;
    u32 p0=0,p1=0,p2=0,hh=0;
    float c=0.f;
    unsigned cnt = SEQ, st2 = 0;
    const unsigned stride = BATCH * INP * 4;

    asm volatile(
        "9:\n\t"
        "s_waitcnt vmcnt(0)\n\t"                         // x(t) loads done
        "v_cvt_pkrtz_f16_f32 %[p0], %[x0], %[x1]\n\t"
        "v_cvt_pkrtz_f16_f32 %[p1], %[x2], %[x3]\n\t"
        "v_cvt_pkrtz_f16_f32 %[p2], %[x4], %[x5]\n\t"
        // prefetch x(t+1)
        "global_load_dword %[x0], %[vo], %[xb] offset:0\n\t"
        "global_load_dword %[x1], %[vo], %[xb] offset:4\n\t"
        "global_load_dword %[x2], %[vo], %[xb] offset:8\n\t"
        "global_load_dword %[x3], %[vo], %[xb] offset:12\n\t"
        "global_load_dword %[x4], %[vo], %[xb] offset:16\n\t"
        "global_load_dword %[x5], %[vo], %[xb] offset:20\n\t"
        "s_cmp_ge_u32 %[cnt], 3\n\t"                     // freeze near end (no OOB)
        "s_cselect_b32 %[st2], %[st], 0\n\t"
        "v_add_u32 %[vo], %[st2], %[vo]\n\t"
        // h row (15 dwords = 30 f16), broadcast within half
        "ds_read_b32 %[h0],  %[ha] offset:0\n\t"
        "ds_read_b32 %[h1],  %[ha] offset:4\n\t"
        "ds_read_b32 %[h2],  %[ha] offset:8\n\t"
        "ds_read_b32 %[h3],  %[ha] offset:12\n\t"
        "ds_read_b32 %[h4],  %[ha] offset:16\n\t"
        "ds_read_b32 %[h5],  %[ha] offset:20\n\t"
        "ds_read_b32 %[h6],  %[ha] offset:24\n\t"
        "ds_read_b32 %[h7],  %[ha] offset:28\n\t"
        "ds_read_b32 %[h8],  %[ha] offset:32\n\t"
        "ds_read_b32 %[h9],  %[ha] offset:36\n\t"
        "ds_read_b32 %[h10], %[ha] offset:40\n\t"
        "ds_read_b32 %[h11], %[ha] offset:44\n\t"
        "ds_read_b32 %[h12], %[ha] offset:48\n\t"
        "ds_read_b32 %[h13], %[ha] offset:52\n\t"
        "ds_read_b32 %[h14], %[ha] offset:56\n\t"
        // acc init (biases into even chains)
        "v_mov_b32 %[a0], %[bi0]\n\t"
        "v_mov_b32 %[a1], %[bi1]\n\t"
        "v_mov_b32 %[a2], %[bi2]\n\t"
        "v_mov_b32 %[a3], %[bi3]\n\t"
        "v_mov_b32 %[a4], 0\n\t"
        "v_mov_b32 %[a5], 0\n\t"
        "v_mov_b32 %[a6], 0\n\t"
        "v_mov_b32 %[a7], 0\n\t"
        "s_waitcnt lgkmcnt(0)\n\t"
        // 60 h-dots: even j -> a0..a3, odd j -> a4..a7 (8 indep chains)
        "v_dot2_f32_f16 %[a0], %[w0],  %[h0],  %[a0]\n\t"
        "v_dot2_f32_f16 %[a1], %[w15], %[h0],  %[a1]\n\t"
        "v_dot2_f32_f16 %[a2], %[w30], %[h0],  %[a2]\n\t"
        "v_dot2_f32_f16 %[a3], %[w45], %[h0],  %[a3]\n\t"
        "v_dot2_f32_f16 %[a4], %[w1],  %[h1],  %[a4]\n\t"
        "v_dot2_f32_f16 %[a5], %[w16], %[h1],  %[a5]\n\t"
        "v_dot2_f32_f16 %[a6], %[w31], %[h1],  %[a6]\n\t"
        "v_dot2_f32_f16 %[a7], %[w46], %[h1],  %[a7]\n\t"
        "v_dot2_f32_f16 %[a0], %[w2],  %[h2],  %[a0]\n\t"
        "v_dot2_f32_f16 %[a1], %[w17], %[h2],  %[a1]\n\t"
        "v_dot2_f32_f16 %[a2], %[w32], %[h2],  %[a2]\n\t"
        "v_dot2_f32_f16 %[a3], %[w47], %[h2],  %[a3]\n\t"
        "v_dot2_f32_f16 %[a4], %[w3],  %[h3],  %[a4]\n\t"
        "v_dot2_f32_f16 %[a5], %[w18], %[h3],  %[a5]\n\t"
        "v_dot2_f32_f16 %[a6], %[w33], %[h3],  %[a6]\n\t"
        "v_dot2_f32_f16 %[a7], %[w48], %[h3],  %[a7]\n\t"
        "v_dot2_f32_f16 %[a0], %[w4],  %[h4],  %[a0]\n\t"
        "v_dot2_f32_f16 %[a1], %[w19], %[h4],  %[a1]\n\t"
        "v_dot2_f32_f16 %[a2], %[w34], %[h4],  %[a2]\n\t"
        "v_dot2_f32_f16 %[a3], %[w49], %[h4],  %[a3]\n\t"
        "v_dot2_f32_f16 %[a4], %[w5],  %[h5],  %[a4]\n\t"
        "v_dot2_f32_f16 %[a5], %[w20], %[h5],  %[a5]\n\t"
        "v_dot2_f32_f16 %[a6], %[w35], %[h5],  %[a6]\n\t"
        "v_dot2_f32_f16 %[a7], %[w50], %[h5],  %[a7]\n\t"
        "v_dot2_f32_f16 %[a0], %[w6],  %[h6],  %[a0]\n\t"
        "v_dot2_f32_f16 %[a1], %[w21], %[h6],  %[a1]\n\t"
        "v_dot2_f32_f16 %[a2], %[w36], %[h6],  %[a2]\n\t"
        "v_dot2_f32_f16 %[a3], %[w51], %[h6],  %[a3]\n\t"
        "v_dot2_f32_f16 %[a4], %[w7],  %[h7],  %[a4]\n\t"
        "v_dot2_f32_f16 %[a5], %[w22], %[h7],  %[a5]\n\t"
        "v_dot2_f32_f16 %[a6], %[w37], %[h7],  %[a6]\n\t"
        "v_dot2_f32_f16 %[a7], %[w52], %[h7],  %[a7]\n\t"
        "v_dot2_f32_f16 %[a0], %[w8],  %[h8],  %[a0]\n\t"
        "v_dot2_f32_f16 %[a1], %[w23], %[h8],  %[a1]\n\t"
        "v_dot2_f32_f16 %[a2], %[w38], %[h8],  %[a2]\n\t"
        "v_dot2_f32_f16 %[a3], %[w53], %[h8],  %[a3]\n\t"
        "v_dot2_f32_f16 %[a4], %[w9],  %[h9],  %[a4]\n\t"
        "v_dot2_f32_f16 %[a5], %[w24], %[h9],  %[a5]\n\t"
        "v_dot2_f32_f16 %[a6], %[w39], %[h9],  %[a6]\n\t"
        "v_dot2_f32_f16 %[a7], %[w54], %[h9],  %[a7]\n\t"
        "v_dot2_f32_f16 %[a0], %[w10], %[h10], %[a0]\n\t"
        "v_dot2_f32_f16 %[a1], %[w25], %[h10], %[a1]\n\t"
        "v_dot2_f32_f16 %[a2], %[w40], %[h10], %[a2]\n\t"
        "v_dot2_f32_f16 %[a3], %[w55], %[h10], %[a3]\n\t"
        "v_dot2_f32_f16 %[a4], %[w11], %[h11], %[a4]\n\t"
        "v_dot2_f32_f16 %[a5], %[w26], %[h11], %[a5]\n\t"
        "v_dot2_f32_f16 %[a6], %[w41], %[h11], %[a6]\n\t"
        "v_dot2_f32_f16 %[a7], %[w56], %[h11], %[a7]\n\t"
        "v_dot2_f32_f16 %[a0], %[w12], %[h12], %[a0]\n\t"
        "v_dot2_f32_f16 %[a1], %[w27], %[h12], %[a1]\n\t"
        "v_dot2_f32_f16 %[a2], %[w42], %[h12], %[a2]\n\t"
        "v_dot2_f32_f16 %[a3], %[w57], %[h12], %[a3]\n\t"
        "v_dot2_f32_f16 %[a4], %[w13], %[h13], %[a4]\n\t"
        "v_dot2_f32_f16 %[a5], %[w28], %[h13], %[a5]\n\t"
        "v_dot2_f32_f16 %[a6], %[w43], %[h13], %[a6]\n\t"
        "v_dot2_f32_f16 %[a7], %[w58], %[h13], %[a7]\n\t"
        "v_dot2_f32_f16 %[a0], %[w14], %[h14], %[a0]\n\t"
        "v_dot2_f32_f16 %[a1], %[w29], %[h14], %[a1]\n\t"
        "v_dot2_f32_f16 %[a2], %[w44], %[h14], %[a2]\n\t"
        "v_dot2_f32_f16 %[a3], %[w59], %[h14], %[a3]\n\t"
        // 12 x-dots
        "v_dot2_f32_f16 %[a4], %[xw0],  %[p0], %[a4]\n\t"
        "v_dot2_f32_f16 %[a5], %[xw3],  %[p0], %[a5]\n\t"
        "v_dot2_f32_f16 %[a6], %[xw6],  %[p0], %[a6]\n\t"
        "v_dot2_f32_f16 %[a7], %[xw9],  %[p0], %[a7]\n\t"
        "v_dot2_f32_f16 %[a0], %[xw1],  %[p1], %[a0]\n\t"
        "v_dot2_f32_f16 %[a1], %[xw4],  %[p1], %[a1]\n\t"
        "v_dot2_f32_f16 %[a2], %[xw7],  %[p1], %[a2]\n\t"
        "v_dot2_f32_f16 %[a3], %[xw10], %[p1], %[a3]\n\t"
        "v_dot2_f32_f16 %[a4], %[xw2],  %[p2], %[a4]\n\t"
        "v_dot2_f32_f16 %[a5], %[xw5],  %[p2], %[a5]\n\t"
        "v_dot2_f32_f16 %[a6], %[xw8],  %[p2], %[a6]\n\t"
        "v_dot2_f32_f16 %[a7], %[xw11], %[p2], %[a7]\n\t"
        // gate sums
        "v_add_f32 %[a0], %[a0], %[a4]\n\t"
        "v_add_f32 %[a1], %[a1], %[a5]\n\t"
        "v_add_f32 %[a2], %[a2], %[a6]\n\t"
        "v_add_f32 %[a3], %[a3], %[a7]\n\t"
        // nonlin: si=t0, sf=t1, tg=t2, so=t3  (exp2-based, 4 streamed chains)
        "v_mul_f32 %[t0], %[nl], %[a0]\n\t"
        "v_mul_f32 %[t1], %[nl], %[a1]\n\t"
        "v_mul_f32 %[t2], %[l2], %[a2]\n\t"
        "v_mul_f32 %[t3], %[nl], %[a3]\n\t"
        "v_exp_f32 %[t0], %[t0]\n\t"
        "v_exp_f32 %[t1], %[t1]\n\t"
        "v_exp_f32 %[t2], %[t2]\n\t"
        "v_exp_f32 %[t3], %[t3]\n\t"
        "v_add_f32 %[t0], 1.0, %[t0]\n\t"
        "v_add_f32 %[t1], 1.0, %[t1]\n\t"
        "v_add_f32 %[t2], 1.0, %[t2]\n\t"
        "v_add_f32 %[t3], 1.0, %[t3]\n\t"
        "v_rcp_f32 %[t0], %[t0]\n\t"
        "v_rcp_f32 %[t1], %[t1]\n\t"
        "v_rcp_f32 %[t2], %[t2]\n\t"
        "v_rcp_f32 %[t3], %[t3]\n\t"
        "v_add_f32 %[t4], %[t2], %[t2]\n\t"      // tg = 1 - 2*rcp
        "v_sub_f32 %[t2], 1.0, %[t4]\n\t"
        "v_mul_f32 %[t5], %[t0], %[t2]\n\t"      // si*tg
        "v_fma_f32 %[c], %[t1], %[c], %[t5]\n\t" // c = sf*c + si*tg
        "v_mul_f32 %[t6], %[l2], %[c]\n\t"       // tanh(c)
        "v_exp_f32 %[t6], %[t6]\n\t"
        "s_nop 0\n\t"
        "v_add_f32 %[t6], 1.0, %[t6]\n\t"
        "v_rcp_f32 %[t6], %[t6]\n\t"
        "s_nop 0\n\t"
        "v_add_f32 %[t7], %[t6], %[t6]\n\t"
        "v_sub_f32 %[t6], 1.0, %[t7]\n\t"
        "v_mul_f32 %[t7], %[t3], %[t6]\n\t"      // h = so*tanh(c)
        "v_cvt_f16_f32 %[hh], %[t7]\n\t"
        "ds_write_b16 %[wa], %[hh]\n\t"
        // loop
        "s_sub_u32 %[cnt], %[cnt], 1\n\t"
        "s_cmp_lg_u32 %[cnt], 0\n\t"
        "s_cbranch_scc1 9b\n\t"
        "s_waitcnt vmcnt(0) lgkmcnt(0)\n\t"
        : [a0]"+v"(a0),[a1]"+v"(a1),[a2]"+v"(a2),[a3]"+v"(a3),
          [a4]"+v"(a4),[a5]"+v"(a5),[a6]"+v"(a6),[a7]"+v"(a7),
          [t0]"+v"(t0),[t1]"+v"(t1),[t2]"+v"(t2),[t3]"+v"(t3),
          [t4]"+v"(t4),[t5]"+v"(t5),[t6]"+v"(t6),[t7]"+v"(t7),
          [h0]"+v"(h0),[h1]"+v"(h1),[h2]"+v"(h2),[h3]"+v"(h3),
          [h4]"+v"(h4),[h5]"+v"(h5),[h6]"+v"(h6),[h7]"+v"(h7),
          [h8]"+v"(h8),[h9]"+v"(h9),[h10]"+v"(h10),[h11]"+v"(h11),
          [h12]"+v"(h12),[h13]"+v"(h13),[h14]"+v"(h14),
          [p0]"+v"(p0),[p1]"+v"(p1),[p2]"+v"(p2),[hh]"+v"(hh),
          [c]"+v"(c),
          [x0]"+v"(x0),[x1]"+v"(x1),[x2]"+v"(x2),
          [x3]"+v"(x3),[x4]"+v"(x4),[x5]"+v"(x5),
          [vo]"+v"(vo),[cnt]"+s"(cnt),[st2]"+s"(st2)
        : [w0]"v"(W[0]),[w1]"v"(W[1]),[w2]"v"(W[2]),[w3]"v"(W[3]),[w4]"v"(W[4]),
          [w5]"v"(W[5]),[w6]"v"(W[6]),[w7]"v"(W[7]),[w8]"v"(W[8]),[w9]"v"(W[9]),
          [w10]"v"(W[10]),[w11]"v"(W[11]),[w12]"v"(W[12]),[w13]"v"(W[13]),[w14]"v"(W[14]),
          [w15]"v"(W[15]),[w16]"v"(W[16]),[w17]"v"(W[17]),[w18]"v"(W[18]),[w19]"v"(W[19]),
          [w20]"v"(W[20]),[w21]"v"(W[21]),[w22]"v"(W[22]),[w23]"v"(W[23]),[w24]"v"(W[24]),
          [w25]"v"(W[25]),[w26]"v"(W[26]),[w27]"v"(W[27]),[w28]"v"(W[28]),[w29]"v"(W[29]),
          [w30]"v"(W[30]),[w31]"v"(W[31]),[w32]"v"(W[32]),[w33]"v"(W[33]),[w34]"v"(W[34]),
          [w35]"v"(W[35]),[w36]"v"(W[36]),[w37]"v"(W[37]),[w38]"v"(W[38]),[w39]"v"(W[39]),
          [w40]"v"(W[40]),[w41]"v"(W[41]),[w42]"v"(W[42]),[w43]"v"(W[43]),[w44]"v"(W[44]),
          [w45]"v"(W[45]),[w46]"v"(W[46]),[w47]"v"(W[47]),[w48]"v"(W[48]),[w49]"v"(W[49]),
          [w50]"v"(W[50]),[w51]"v"(W[51]),[w52]"v"(W[52]),[w53]"v"(W[53]),[w54]"v"(W[54]),
          [w55]"v"(W[55]),[w56]"v"(W[56]),[w57]"v"(W[57]),[w58]"v"(W[58]),[w59]"v"(W[59]),
          [xw0]"v"(XW[0]),[xw1]"v"(XW[1]),[xw2]"v"(XW[2]),[xw3]"v"(XW[3]),
          [xw4]"v"(XW[4]),[xw5]"v"(XW[5]),[xw6]"v"(XW[6]),[xw7]"v"(XW[7]),
          [xw8]"v"(XW[8]),[xw9]"v"(XW[9]),[xw10]"v"(XW[10]),[xw11]"v"(XW[11]),
          [bi0]"v"(B0),[bi1]"v"(B1),[bi2]"v"(B2),[bi3]"v"(B3),
          [nl]"v"(NL),[l2]"v"(L2),
          [ha]"v"(ha),[wa]"v"(wa),
          [xb]"s"(xbase),[st]"s"(stride)
        : "vcc","scc","memory");

    // ---- FC1 (lanes u<30, both halves) — R9-verified epilogue ----
    if (act) {
        float a1v = b1[u];
        const float* w1r = W1 + u * HID;
        #pragma unroll
        for (int k = 0; k < HID; ++k) a1v = fmaf(w1r[k], (float)h_sh[half][k], a1v);
        o1_sh[half][u] = a1v;
    }
    asm volatile("s_waitcnt lgkmcnt(0)" ::: "memory");

    // ---- FC2: out[b][o] for o = u, u+30 (u=0 also 60) ----
    if (act) {
        for (int o = u; o < NOUT; o += HID) {
            float a2v = b2[o];
            const float* w2r = W2 + o * HID;
            #pragma unroll
            for (int k = 0; k < HID; ++k) a2v = fmaf(w2r[k], o1_sh[half][k], a2v);
            out[(size_t)b * NOUT + o] = a2v;
        }
    }
}

extern "C" void kernel_launch(void* const* d_in, const int* in_sizes, int n_in,
                              void* d_out, int out_size, void* d_ws, size_t ws_size,
                              hipStream_t stream) {
    const float* X   = (const float*)d_in[0];
    const float* Wih = (const float*)d_in[1];
    const float* Whh = (const float*)d_in[2];
    const float* bih = (const float*)d_in[3];
    const float* bhh = (const float*)d_in[4];
    const float* W1  = (const float*)d_in[5];
    const float* b1  = (const float*)d_in[6];
    const float* W2  = (const float*)d_in[7];
    const float* b2  = (const float*)d_in[8];
    float* out = (float*)d_out;

    dim3 grid(BATCH / 2);   // 2048 single-wave blocks (2 elems each) -> 2 waves/SIMD
    dim3 block(64);
    hipLaunchKernelGGL(lstm_asm, grid, block, 0, stream,
                       X, Wih, Whh, bih, bhh, W1, b1, W2, b2, out);
}

// Round 14
// 316.978 us; speedup vs baseline: 1.7873x; 1.0217x over previous
//
#include <hip/hip_runtime.h>

// LSTMNet: SEQ=600, B=4096, IN=6, H=30, OUT=61, fp32 in/out.
// M4: one wave = 4 batch elements, fully self-contained (NO barriers).
// 1024 single-wave blocks -> 1 wave/SIMD, all 1024 SIMDs active.
//   Weight matrix rows GATE-INTERLEAVED: row R = gate(R&3), unit(R>>2).
//   Per step: C[m] = Ah[m] x Bh + xacc[m]   (8 chained MFMA, m=0..7)
//             xacc'[m] = Ax[m] x Bx(x_{t+1})  (8 off-chain MFMA, x 1 iter ahead)
//   C layout (m89-verified): col=lane&15=elem, row=4*(l>>4)+reg ->
//   lane (g,b<4): C[m] = (i,f,g,o) of unit 4m+g, elem b  (gates pre-grouped!)
//   C -> nonlin: wave-private LDS scatter (16 lanes, 8xb128) + gather
//   (64 lanes, 2xb128) -> 2 units/lane => trans issue at the chip floor.
//   h -> B-frag: 4x ds_bpermute (src lane 16b+4g+d); pair-15 = (0,1.0) bias
//   slot overwritten with 0x3C000000 (R10-verified).
// Weights are MFMA A-operands -> AGPR residency is free (R10-12 evidence).

#define SEQ    600
#define BATCH  4096
#define INP    6
#define HID    30
#define NOUT   61
#define LOG2E  1.4426950408889634f
#define LOG2E2 2.8853900817779268f

typedef __fp16 f16;
typedef f16  f16x2 __attribute__((ext_vector_type(2)));
typedef f16  f16x8 __attribute__((ext_vector_type(8)));
typedef float f32x2 __attribute__((ext_vector_type(2)));
typedef float f32x4 __attribute__((ext_vector_type(4)));

__device__ __forceinline__ float rcp_(float x)  { return __builtin_amdgcn_rcpf(x); }
__device__ __forceinline__ float exp2_(float x) { return __builtin_amdgcn_exp2f(x); }
__device__ __forceinline__ unsigned cvtpk(float a, float b) {
    union { f16x2 h; unsigned u; } c;
    c.h = __builtin_amdgcn_cvt_pkrtz(a, b);
    return c.u;
}
__device__ __forceinline__ f16x8 mk8(unsigned a, unsigned b, unsigned c, unsigned d) {
    union { unsigned u[4]; f16x8 v; } x;
    x.u[0] = a; x.u[1] = b; x.u[2] = c; x.u[3] = d;
    return x.v;
}
__device__ __forceinline__ float sigm_(float x) {
    return rcp_(1.0f + exp2_(-LOG2E * x));
}
__device__ __forceinline__ float tanh_(float x) {
    return fmaf(-2.0f, rcp_(exp2_(LOG2E2 * x) + 1.0f), 1.0f);
}

extern "C" __global__ void __launch_bounds__(64, 1)
lstm_m4(const float* __restrict__ X,   const float* __restrict__ Wih,
        const float* __restrict__ Whh, const float* __restrict__ bih,
        const float* __restrict__ bhh, const float* __restrict__ W1,
        const float* __restrict__ b1,  const float* __restrict__ W2,
        const float* __restrict__ b2,  float* __restrict__ out)
{
    // [elem][unit*4+gate] f32; elem stride 136 words -> scatter is 2-way (free)
    __shared__ __align__(16) float scr[4][136];
    __shared__ float h32[4][32];
    __shared__ float o1s[4][32];

    const int l  = threadIdx.x;     // 0..63
    const int g  = l >> 4;          // MFMA k-group; nonlin ELEM
    const int b  = l & 15;          // MFMA col (elem b<4); nonlin UNIT-PAIR v
    const int e0 = blockIdx.x * 4;  // first elem of this wave

    // ---- pack A fragments (gate-interleaved rows; R10-verified frag map) ----
    f16x8 Ah[8], Ax[8];
    {
        const int q = b & 3;              // gate of this lane's rows
        #pragma unroll
        for (int m = 0; m < 8; ++m) {
            const int u  = 4 * m + (b >> 2);   // unit
            const bool ov = (u < HID);
            const int row = q * HID + (ov ? u : 0);
            unsigned dh[4], dx[4];
            #pragma unroll
            for (int jp = 0; jp < 4; ++jp) {
                const int k0 = 8 * g + 2 * jp, k1 = k0 + 1;
                float v0 = (ov && k0 < HID) ? Whh[row * HID + k0] : 0.f;
                float v1 = (ov && k1 < HID) ? Whh[row * HID + k1]
                         : ((ov && k1 == 31) ? (bih[row] + bhh[row]) : 0.f);
                dh[jp] = cvtpk(v0, v1);
                float w0 = (ov && k0 < INP) ? Wih[row * INP + k0] : 0.f;
                float w1 = (ov && k1 < INP) ? Wih[row * INP + k1] : 0.f;
                dx[jp] = cvtpk(w0, w1);
            }
            Ah[m] = mk8(dh[0], dh[1], dh[2], dh[3]);
            Ax[m] = mk8(dx[0], dx[1], dx[2], dx[3]);
        }
    }

    // bpermute addrs: Bh dword d comes from lane 16*b + 4*g + d (its P reg)
    const int ad0 = ((16 * b + 4 * g + 0) & 63) * 4;
    const int ad1 = ((16 * b + 4 * g + 1) & 63) * 4;
    const int ad2 = ((16 * b + 4 * g + 2) & 63) * 4;
    const int ad3 = ((16 * b + 4 * g + 3) & 63) * 4;
    const bool isg3 = (g == 3);

    // per-lane x source: elem b&3 (cols 4..15 duplicate col b&3 -> harmless)
    const float* xsrc = X + (size_t)(e0 + (b & 3)) * INP;

    unsigned P = 0;                    // this lane's h pair (units 2b, 2b+1), elem g
    float cA = 0.f, cB = 0.f;          // cell state for units 2b, 2b+1
    float hA = 0.f, hB = 0.f;

    f32x2 xq0, xq1, xq2;
    { const float* p = xsrc; xq0 = *(const f32x2*)p; xq1 = *(const f32x2*)(p+2); xq2 = *(const f32x2*)(p+4); }

    f32x4 xcA[8], xcB[8];
    const f32x4 ZZ = {0.f, 0.f, 0.f, 0.f};

    #define XACC(DST) do {                                                     \
        const unsigned c0 = cvtpk(xq0.x, xq0.y);                               \
        const unsigned c1 = cvtpk(xq1.x, xq1.y);                               \
        const unsigned c2 = cvtpk(xq2.x, xq2.y);                               \
        const f16x8 Bx = mk8(g == 0 ? c0 : 0u, g == 0 ? c1 : 0u,               \
                             g == 0 ? c2 : 0u, 0u);                            \
        _Pragma("unroll")                                                      \
        for (int m = 0; m < 8; ++m)                                            \
            DST[m] = __builtin_amdgcn_mfma_f32_16x16x32_f16(Ax[m], Bx, ZZ, 0, 0, 0); \
    } while (0)

    XACC(xcA);                                   // x-projection for t = 0
    { const float* p = xsrc + (size_t)BATCH * INP;   // x(1)
      xq0 = *(const f32x2*)p; xq1 = *(const f32x2*)(p+2); xq2 = *(const f32x2*)(p+4); }

    #define ITER(XC, XN, T) do {                                               \
        /* Bh from P via 4 bpermutes; pair-15 = (0, 1.0) bias slot */          \
        unsigned d0 = (unsigned)__builtin_amdgcn_ds_bpermute(ad0, (int)P);     \
        unsigned d1 = (unsigned)__builtin_amdgcn_ds_bpermute(ad1, (int)P);     \
        unsigned d2 = (unsigned)__builtin_amdgcn_ds_bpermute(ad2, (int)P);     \
        unsigned d3 = (unsigned)__builtin_amdgcn_ds_bpermute(ad3, (int)P);     \
        d3 = isg3 ? 0x3C000000u : d3;                                          \
        const f16x8 Bh = mk8(d0, d1, d2, d3);                                  \
        f32x4 C[8];                                                            \
        _Pragma("unroll")                                                      \
        for (int m = 0; m < 8; ++m)                                            \
            C[m] = __builtin_amdgcn_mfma_f32_16x16x32_f16(Ah[m], Bh, XC[m], 0, 0, 0); \
        /* off-chain: x-projection for step T+1 from x regs loaded last iter */\
        XACC(XN);                                                              \
        /* issue x loads for step T+2 */                                       \
        { int tt = (T) + 2; if (tt > SEQ - 1) tt = SEQ - 1;                    \
          const float* p = xsrc + (size_t)tt * BATCH * INP;                    \
          xq0 = *(const f32x2*)p; xq1 = *(const f32x2*)(p+2);                  \
          xq2 = *(const f32x2*)(p+4); }                                        \
        /* scatter C: 16 real-col lanes write [elem][unit][gate] */            \
        if (b < 4) {                                                           \
            _Pragma("unroll")                                                  \
            for (int m = 0; m < 8; ++m)                                        \
                *(f32x4*)&scr[b][(4 * m + g) * 4] = C[m];                      \
        }                                                                      \
        /* gather: this lane's units 2b, 2b+1 of elem g */                     \
        const f32x4 gA = *(const f32x4*)&scr[g][(2 * b) * 4];                  \
        const f32x4 gB = *(const f32x4*)&scr[g][(2 * b + 1) * 4];              \
        /* nonlin: gA/gB = (i,f,g,o) */                                        \
        const float siA = sigm_(gA.x), sfA = sigm_(gA.y);                      \
        const float tgA = tanh_(gA.z), soA = sigm_(gA.w);                      \
        const float siB = sigm_(gB.x), sfB = sigm_(gB.y);                      \
        const float tgB = tanh_(gB.z), soB = sigm_(gB.w);                      \
        cA = fmaf(sfA, cA, siA * tgA);                                         \
        cB = fmaf(sfB, cB, siB * tgB);                                         \
        hA = soA * tanh_(cA);                                                  \
        hB = soB * tanh_(cB);                                                  \
        P = cvtpk(hA, hB);                                                     \
    } while (0)

    for (int t = 0; t < SEQ; t += 2) {
        ITER(xcA, xcB, t);
        ITER(xcB, xcA, t + 1);
    }
    #undef ITER
    #undef XACC

    // ---- epilogue: lane (g, b=v) holds h of elem g, units 2v, 2v+1 ----
    if (b < 15) {
        h32[g][2 * b]     = hA;
        h32[g][2 * b + 1] = hB;
    }
    asm volatile("s_waitcnt lgkmcnt(0)" ::: "memory");   // single wave

    // FC1: lane (g, j): rows j and j+16 (j<14) of elem g
    {
        float hr[HID];
        #pragma unroll
        for (int k = 0; k < HID; ++k) hr[k] = h32[g][k];
        float a0 = b1[b];
        const float* w1r0 = W1 + b * HID;
        #pragma unroll
        for (int k = 0; k < HID; ++k) a0 = fmaf(w1r0[k], hr[k], a0);
        o1s[g][b] = a0;
        if (b < 14) {
            float a1 = b1[b + 16];
            const float* w1r1 = W1 + (b + 16) * HID;
            #pragma unroll
            for (int k = 0; k < HID; ++k) a1 = fmaf(w1r1[k], hr[k], a1);
            o1s[g][b + 16] = a1;
        }
    }
    asm volatile("s_waitcnt lgkmcnt(0)" ::: "memory");

    // FC2: lane (g, j): rows j, j+16, j+32, j+48 (<61) of elem g
    {
        float orr[HID];
        #pragma unroll
        for (int k = 0; k < HID; ++k) orr[k] = o1s[g][k];
        #pragma unroll
        for (int r = 0; r < 4; ++r) {
            const int o = b + 16 * r;
            if (o < NOUT) {
                float a2 = b2[o];
                const float* w2r = W2 + o * HID;
                #pragma unroll
                for (int k = 0; k < HID; ++k) a2 = fmaf(w2r[k], orr[k], a2);
                out[(size_t)(e0 + g) * NOUT + o] = a2;
            }
        }
    }
}

extern "C" void kernel_launch(void* const* d_in, const int* in_sizes, int n_in,
                              void* d_out, int out_size, void* d_ws, size_t ws_size,
                              hipStream_t stream) {
    const float* X   = (const float*)d_in[0];
    const float* Wih = (const float*)d_in[1];
    const float* Whh = (const float*)d_in[2];
    const float* bih = (const float*)d_in[3];
    const float* bhh = (const float*)d_in[4];
    const float* W1  = (const float*)d_in[5];
    const float* b1  = (const float*)d_in[6];
    const float* W2  = (const float*)d_in[7];
    const float* b2  = (const float*)d_in[8];
    float* out = (float*)d_out;

    dim3 grid(BATCH / 4);   // 1024 single-wave blocks -> 1 wave per SIMD
    dim3 block(64);
    hipLaunchKernelGGL(lstm_m4, grid, block, 0, stream,
                       X, Wih, Whh, bih, bhh, W1, b1, W2, b2, out);
}